// Round 3
// baseline (330.322 us; speedup 1.0000x reference)
//
#include <hip/hip_runtime.h>
#include <hip/hip_bf16.h>

// VQ-VAE vector quantizer: B=32768, K=4096, D=256 (fp32)
// out = [quantized (B*D floats), vq_loss (1 float)]
//
// Primary path (needs ~6.3MB ws):
//  xconv : X -> bf16 hi/lo, swizzled into d_out (32MB, overwritten later)
//  econv : E -> NEGATED bf16 hi/lo, swizzled into ws
//  en2ext: E-ext tile {0.5||e||^2 as bf16 hi/lo} into ws (folds ||e||^2 into GEMM)
//  dist2 : counted-vmcnt 2-deep pipelined MFMA GEMM (3 bf16 terms + ext slice),
//          acc = 0.5||e||^2 - x.e directly; per-row top-2 per 1024-code chunk
//  rescore: fp64 rescore of 8 candidates -> exact winner, gather, loss partials
//  finalize: loss = 1.25 * mean((x-q)^2)
// Fallback path (R2, proven): used if ws_size too small.

#define B_N 32768
#define K_N 4096
#define D_N 256

typedef short bf16x8 __attribute__((ext_vector_type(8)));
typedef float f32x4 __attribute__((ext_vector_type(4)));
typedef unsigned int uint4v __attribute__((ext_vector_type(4)));
typedef unsigned short u16;

// ---------- primary ws layout ----------
#define NCH 4
static constexpr size_t P_TOP2 = 0;                                  // 32768*4*16 = 2 MB
static constexpr size_t P_ESW  = (size_t)B_N * NCH * 16;             // +4 MB
static constexpr size_t P_EXT  = P_ESW + (size_t)K_N * D_N * 4;      // +256 KB
static constexpr size_t P_PART = P_EXT + 32 * 8192;                  // +4 KB
static constexpr size_t P_NEED = P_PART + 512 * 8;

// ---------- fallback (R2) ws layout ----------
#define NCHF 2
static constexpr size_t F_TOP2 = 0;
static constexpr size_t F_EN2  = (size_t)B_N * NCHF * 16;
static constexpr size_t F_PART = F_EN2 + (size_t)K_N * 4;

__device__ __forceinline__ u16 f2bf(float f) {
    return (u16)__builtin_bit_cast(unsigned short, __float2bfloat16(f));
}
__device__ __forceinline__ float bfhi2f(u16 h) { return __uint_as_float(((unsigned)h) << 16); }

__device__ __forceinline__ void gload_lds16(const void* g, void* l) {
    __builtin_amdgcn_global_load_lds(
        (const __attribute__((address_space(1))) void*)g,
        (__attribute__((address_space(3))) void*)l, 16, 0, 0);
}

#define WAITVM8()  asm volatile("s_waitcnt vmcnt(8)" ::: "memory")
#define WAITVM10() asm volatile("s_waitcnt vmcnt(10)" ::: "memory")
#define BARRIER()  __builtin_amdgcn_s_barrier()

__device__ __forceinline__ void top2_merge(float& v0, int& i0, float& v1, int& i1,
                                           float ov0, int oi0, float ov1, int oi1) {
    bool bf_ = (ov0 < v0) || (ov0 == v0 && oi0 < i0);
    float w0v = bf_ ? ov0 : v0;  int w0i = bf_ ? oi0 : i0;
    float lv  = bf_ ? v0  : ov0; int li  = bf_ ? i0  : oi0;
    float cv  = bf_ ? ov1 : v1;  int ci  = bf_ ? oi1 : i1;
    bool tl = (lv < cv) || (lv == cv && li < ci);
    v0 = w0v; i0 = w0i;
    v1 = tl ? lv : cv; i1 = tl ? li : ci;
}

// ================= primary path =================

// X -> bf16 hi/lo swizzled: byte off = ((((rb*8+h)*2+term)*8+rf)*64+lane)*16
// row = rb*128+rf*16+(lane&15); d = h*32+(lane>>4)*8+j
__global__ void xconv_kernel(const float* __restrict__ X, u16* __restrict__ Xsw) {
    const int gid = blockIdx.x * 256 + threadIdx.x;     // B_N*32 threads
    const int row = gid >> 5;
    const int d0  = (gid & 31) << 3;
    const float4 a = *reinterpret_cast<const float4*>(X + (size_t)row * D_N + d0);
    const float4 b = *reinterpret_cast<const float4*>(X + (size_t)row * D_N + d0 + 4);
    float f[8] = {a.x, a.y, a.z, a.w, b.x, b.y, b.z, b.w};
    unsigned hi[8], lo[8];
    #pragma unroll
    for (int j = 0; j < 8; ++j) {
        hi[j] = f2bf(f[j]);
        lo[j] = f2bf(f[j] - bfhi2f((u16)hi[j]));
    }
    const int rb = row >> 7, rr = row & 127, rf = rr >> 4, llo = rr & 15;
    const int h = d0 >> 5, lhi = (d0 & 31) >> 3, lane = lhi * 16 + llo;
    size_t base = ((size_t)((rb * 8 + h) * 2) * 8 + rf) * 512 + (size_t)lane * 8;  // u16 units
    uint4v hv, lv;
    hv.x = hi[0] | (hi[1] << 16); hv.y = hi[2] | (hi[3] << 16);
    hv.z = hi[4] | (hi[5] << 16); hv.w = hi[6] | (hi[7] << 16);
    lv.x = lo[0] | (lo[1] << 16); lv.y = lo[2] | (lo[3] << 16);
    lv.z = lo[4] | (lo[5] << 16); lv.w = lo[6] | (lo[7] << 16);
    *reinterpret_cast<uint4v*>(Xsw + base) = hv;
    *reinterpret_cast<uint4v*>(Xsw + base + 4096) = lv;   // term stride = 8*64*8 u16
}

// E -> NEGATED bf16 hi/lo swizzled (same geometry, code instead of row)
__global__ void econv_kernel(const float* __restrict__ E, u16* __restrict__ Esw) {
    const int gid = blockIdx.x * 256 + threadIdx.x;     // K_N*32 threads
    const int code = gid >> 5;
    const int d0  = (gid & 31) << 3;
    const float4 a = *reinterpret_cast<const float4*>(E + (size_t)code * D_N + d0);
    const float4 b = *reinterpret_cast<const float4*>(E + (size_t)code * D_N + d0 + 4);
    float f[8] = {a.x, a.y, a.z, a.w, b.x, b.y, b.z, b.w};
    unsigned hi[8], lo[8];
    #pragma unroll
    for (int j = 0; j < 8; ++j) {
        float nf = -f[j];
        hi[j] = f2bf(nf);
        lo[j] = f2bf(nf - bfhi2f((u16)hi[j]));
    }
    const int cbg = code >> 7, cc = code & 127, cf = cc >> 4, llo = cc & 15;
    const int h = d0 >> 5, lhi = (d0 & 31) >> 3, lane = lhi * 16 + llo;
    size_t base = ((size_t)((cbg * 8 + h) * 2) * 8 + cf) * 512 + (size_t)lane * 8;
    uint4v hv, lv;
    hv.x = hi[0] | (hi[1] << 16); hv.y = hi[2] | (hi[3] << 16);
    hv.z = hi[4] | (hi[5] << 16); hv.w = hi[6] | (hi[7] << 16);
    lv.x = lo[0] | (lo[1] << 16); lv.y = lo[2] | (lo[3] << 16);
    lv.z = lo[4] | (lo[5] << 16); lv.w = lo[6] | (lo[7] << 16);
    *reinterpret_cast<uint4v*>(Esw + base) = hv;
    *reinterpret_cast<uint4v*>(Esw + base + 4096) = lv;
}

// E-ext: per code, [en2_hi, en2_lo, 0...] along a K=32 ext slice, B-frag layout.
// Eext byte off = cbg*8192 + cf*1024 + lane*16
__global__ void en2ext_kernel(const float* __restrict__ E, u16* __restrict__ Eext) {
    const int gtid = blockIdx.x * 256 + threadIdx.x;
    const int code = gtid >> 6;
    const int lane = threadIdx.x & 63;
    if (code >= K_N) return;
    const float4 v = *reinterpret_cast<const float4*>(E + (size_t)code * D_N + lane * 4);
    double s = (double)v.x * v.x + (double)v.y * v.y + (double)v.z * v.z + (double)v.w * v.w;
    #pragma unroll
    for (int o = 32; o; o >>= 1) s += __shfl_xor(s, o, 64);
    float en2 = (float)(0.5 * s);
    unsigned uh = f2bf(en2);
    unsigned ul = f2bf(en2 - bfhi2f((u16)uh));
    const int cbg = code >> 7, cc = code & 127, cf = cc >> 4, llo = cc & 15;
    if (lane < 4) {
        uint4v w; w.x = (lane == 0) ? (uh | (ul << 16)) : 0u; w.y = 0; w.z = 0; w.w = 0;
        u16* p = Eext + (size_t)cbg * 4096 + (size_t)cf * 512 + (size_t)(lane * 16 + llo) * 8;
        *reinterpret_cast<uint4v*>(p) = w;
    }
}

// ---------- dist2: pipelined MFMA GEMM + top-2 ----------
// grid (256 rb, 4 chunks), 256 thr (4 waves 2x2), block tile 128 rows x 128 codes
// LDS: buf0 X@0 E@16K | buf1 X@32K E@48K | EXT@64K (8K) -> 72KB
__launch_bounds__(256, 2)
__global__ void dist2_kernel(const char* __restrict__ Xsw, const char* __restrict__ Esw,
                             const char* __restrict__ Eext, float4* __restrict__ top2) {
    __shared__ __align__(16) char lds[73728];
    const int tid  = threadIdx.x;
    const int lane = tid & 63;
    const int wid  = tid >> 6;
    const int wr   = wid >> 1, wc = wid & 1;
    const int llo  = lane & 15, lhi = lane >> 4;
    const int rb = blockIdx.x;
    const int chunk = blockIdx.y;

    const char* xb = Xsw + (size_t)rb * 131072;            // 8 h x 16KB
    const char* eb = Esw + (size_t)chunk * 8 * 131072;     // 8 cb x (8 h x 16KB)
    const char* xe = Eext + (size_t)chunk * 8 * 8192;

    // X-ext A-frag: rows all identical, k=0,1 -> 1.0bf16 (lanes with lhi==0)
    bf16x8 aext;
    #pragma unroll
    for (int j = 0; j < 8; ++j) aext[j] = 0;
    if (lane < 16) { aext[0] = (short)0x3F80; aext[1] = (short)0x3F80; }

    float tv0[16], tv1[16];
    int   tpk[16];
    #pragma unroll
    for (int s = 0; s < 16; ++s) { tv0[s] = 3.4e38f; tv1[s] = 3.4e38f; tpk[s] = -1; }

    f32x4 acc[4][4];
    #pragma unroll
    for (int i = 0; i < 4; ++i)
        #pragma unroll
        for (int j = 0; j < 4; ++j) acc[i][j] = (f32x4){0.f, 0.f, 0.f, 0.f};

    auto STAGE = [&](int cb, int h, int buf) {
        const char* xs = xb + ((size_t)h << 14);
        const char* es = eb + ((size_t)((cb << 3) + h) << 14);
        char* lx = lds + buf * 32768;
        #pragma unroll
        for (int it = 0; it < 4; ++it)
            gload_lds16(xs + it * 4096 + tid * 16, lx + it * 4096 + wid * 1024);
        #pragma unroll
        for (int it = 0; it < 4; ++it)
            gload_lds16(es + it * 4096 + tid * 16, lx + 16384 + it * 4096 + wid * 1024);
    };
    auto STAGE_EXT = [&](int cb) {
        const char* s = xe + (size_t)cb * 8192;
        #pragma unroll
        for (int it = 0; it < 2; ++it)
            gload_lds16(s + it * 4096 + tid * 16, lds + 65536 + it * 4096 + wid * 1024);
    };

    STAGE(0, 0, 0);

    for (int cb = 0; cb < 8; ++cb) {
        #pragma unroll
        for (int h = 0; h < 8; ++h) {
            const int nc = (h == 7) ? ((cb + 1) & 7) : cb;   // cb=7,h=7 wraps to dummy
            STAGE(nc, (h + 1) & 7, (h + 1) & 1);
            if (h == 6) { STAGE_EXT(cb); WAITVM10(); } else { WAITVM8(); }
            BARRIER();

            const bf16x8* LX = reinterpret_cast<const bf16x8*>(lds + (h & 1) * 32768);
            const bf16x8* LE = reinterpret_cast<const bf16x8*>(lds + (h & 1) * 32768 + 16384);
            bf16x8 ah[4], al[4], bh[4], bl[4];
            #pragma unroll
            for (int i = 0; i < 4; ++i) ah[i] = LX[(wr * 4 + i) * 64 + lane];
            #pragma unroll
            for (int j = 0; j < 4; ++j) bh[j] = LE[(wc * 4 + j) * 64 + lane];
            #pragma unroll
            for (int i = 0; i < 4; ++i) al[i] = LX[512 + (wr * 4 + i) * 64 + lane];
            #pragma unroll
            for (int j = 0; j < 4; ++j) bl[j] = LE[512 + (wc * 4 + j) * 64 + lane];

            __builtin_amdgcn_s_setprio(1);
            #pragma unroll
            for (int i = 0; i < 4; ++i)
                #pragma unroll
                for (int j = 0; j < 4; ++j)
                    acc[i][j] = __builtin_amdgcn_mfma_f32_16x16x32_bf16(ah[i], bh[j], acc[i][j], 0, 0, 0);
            #pragma unroll
            for (int i = 0; i < 4; ++i)
                #pragma unroll
                for (int j = 0; j < 4; ++j)
                    acc[i][j] = __builtin_amdgcn_mfma_f32_16x16x32_bf16(al[i], bh[j], acc[i][j], 0, 0, 0);
            #pragma unroll
            for (int i = 0; i < 4; ++i)
                #pragma unroll
                for (int j = 0; j < 4; ++j)
                    acc[i][j] = __builtin_amdgcn_mfma_f32_16x16x32_bf16(ah[i], bl[j], acc[i][j], 0, 0, 0);
            __builtin_amdgcn_s_setprio(0);

            if (h == 7) {
                // ext slice: + 0.5||e||^2
                const bf16x8* LT = reinterpret_cast<const bf16x8*>(lds + 65536);
                bf16x8 be[4];
                #pragma unroll
                for (int j = 0; j < 4; ++j) be[j] = LT[(wc * 4 + j) * 64 + lane];
                __builtin_amdgcn_s_setprio(1);
                #pragma unroll
                for (int i = 0; i < 4; ++i)
                    #pragma unroll
                    for (int j = 0; j < 4; ++j)
                        acc[i][j] = __builtin_amdgcn_mfma_f32_16x16x32_bf16(aext, be[j], acc[i][j], 0, 0, 0);
                __builtin_amdgcn_s_setprio(0);

                // epilogue: top-2 update, acc = 0.5||e||^2 - x.e
                const int codebase = chunk * 1024 + cb * 128;
                #pragma unroll
                for (int j = 0; j < 4; ++j) {
                    const int idx = codebase + (wc * 4 + j) * 16 + llo;
                    #pragma unroll
                    for (int i = 0; i < 4; ++i) {
                        #pragma unroll
                        for (int r = 0; r < 4; ++r) {
                            const float v = acc[i][j][r];
                            const int s = i * 4 + r;
                            const bool c0 = v < tv0[s];
                            const bool c1 = v < tv1[s];
                            const int pk = tpk[s];
                            const int pkA = (pk << 16) | idx;
                            const int pkB = (idx << 16) | (pk & 0xffff);
                            tv1[s] = c0 ? tv0[s] : (c1 ? v : tv1[s]);
                            tv0[s] = c0 ? v : tv0[s];
                            tpk[s] = c0 ? pkA : (c1 ? pkB : pk);
                        }
                    }
                }
                #pragma unroll
                for (int i = 0; i < 4; ++i)
                    #pragma unroll
                    for (int j = 0; j < 4; ++j) acc[i][j] = (f32x4){0.f, 0.f, 0.f, 0.f};
            }
            BARRIER();
        }
    }

    // cross-lane butterfly merge over the 16 column-lanes
    #pragma unroll
    for (int m = 1; m <= 8; m <<= 1) {
        #pragma unroll
        for (int s = 0; s < 16; ++s) {
            float ov0 = __shfl_xor(tv0[s], m, 64);
            float ov1 = __shfl_xor(tv1[s], m, 64);
            int   opk = __shfl_xor(tpk[s], m, 64);
            float v0 = tv0[s], v1 = tv1[s];
            int i0 = tpk[s] & 0xffff, i1 = (tpk[s] >> 16) & 0xffff;
            top2_merge(v0, i0, v1, i1, ov0, opk & 0xffff, ov1, (opk >> 16) & 0xffff);
            tv0[s] = v0; tv1[s] = v1; tpk[s] = (i1 << 16) | i0;
        }
    }

    __syncthreads();
    float4* M = reinterpret_cast<float4*>(lds);   // [128][2]
    if (llo == 0) {
        #pragma unroll
        for (int i = 0; i < 4; ++i)
            #pragma unroll
            for (int r = 0; r < 4; ++r) {
                const int rowl = wr * 64 + i * 16 + lhi * 4 + r;
                const int s = i * 4 + r;
                M[rowl * 2 + wc] = make_float4(tv0[s], __int_as_float(tpk[s] & 0xffff),
                                               tv1[s], __int_as_float((tpk[s] >> 16) & 0xffff));
            }
    }
    __syncthreads();
    if (tid < 128) {
        float4 A4 = M[tid * 2 + 0], B4 = M[tid * 2 + 1];
        float v0 = A4.x, v1 = A4.z;
        int i0 = __float_as_int(A4.y), i1 = __float_as_int(A4.w);
        top2_merge(v0, i0, v1, i1, B4.x, __float_as_int(B4.y), B4.z, __float_as_int(B4.w));
        top2[(size_t)(rb * 128 + tid) * NCH + chunk] =
            make_float4(v0, __int_as_float(i0), v1, __int_as_float(i1));
    }
}

// ---------- rescore (template over candidate chunks) ----------
template <int NC>
__global__ void rescore_kernel(const float* __restrict__ X, const float* __restrict__ E,
                               const float4* __restrict__ top2, float* __restrict__ out,
                               double* __restrict__ partials) {
    const int lane = threadIdx.x & 63;
    const int wid  = (blockIdx.x * blockDim.x + threadIdx.x) >> 6;
    const int nw   = (gridDim.x * blockDim.x) >> 6;
    double wloc = 0.0;

    for (int row = wid; row < B_N; row += nw) {
        int cand[2 * NC];
        #pragma unroll
        for (int c = 0; c < NC; ++c) {
            float4 t = top2[(size_t)row * NC + c];
            cand[2 * c]     = __float_as_int(t.y);
            cand[2 * c + 1] = __float_as_int(t.w);
        }
        const float4 xv = *reinterpret_cast<const float4*>(X + (size_t)row * D_N + lane * 4);

        double bestd = 1e300; int besti = 0x7fffffff;
        float4 beste = make_float4(0.f, 0.f, 0.f, 0.f);
        #pragma unroll
        for (int c = 0; c < 2 * NC; ++c) {
            const int k = cand[c];
            const float4 ev = *reinterpret_cast<const float4*>(E + (size_t)k * D_N + lane * 4);
            double dx = (double)xv.x - (double)ev.x;
            double dy = (double)xv.y - (double)ev.y;
            double dz = (double)xv.z - (double)ev.z;
            double dw = (double)xv.w - (double)ev.w;
            double s = dx * dx + dy * dy + dz * dz + dw * dw;
            #pragma unroll
            for (int o = 32; o; o >>= 1) s += __shfl_xor(s, o, 64);
            if (s < bestd || (s == bestd && k < besti)) { bestd = s; besti = k; beste = ev; }
        }
        *reinterpret_cast<float4*>(out + (size_t)row * D_N + lane * 4) = beste;
        wloc += bestd;
    }

    __shared__ double bsum[8];
    const int widx = threadIdx.x >> 6;
    if (lane == 0) bsum[widx] = wloc;
    __syncthreads();
    if (threadIdx.x == 0) {
        double s = 0.0;
        for (int w = 0; w < (int)(blockDim.x >> 6); ++w) s += bsum[w];
        partials[blockIdx.x] = s;
    }
}

__global__ void finalize_kernel(const double* __restrict__ partials, int n,
                                float* __restrict__ loss_out) {
    __shared__ double sm[256];
    double s = 0.0;
    for (int i = threadIdx.x; i < n; i += 256) s += partials[i];
    sm[threadIdx.x] = s;
    __syncthreads();
    for (int st = 128; st; st >>= 1) {
        if (threadIdx.x < st) sm[threadIdx.x] += sm[threadIdx.x + st];
        __syncthreads();
    }
    if (threadIdx.x == 0)
        *loss_out = (float)(1.25 * sm[0] / (double)((size_t)B_N * D_N));
}

// ================= fallback path (R2, proven) =================

__global__ void xconv_f(const float* __restrict__ X, u16* __restrict__ Xsw) {
    const int gid = blockIdx.x * 256 + threadIdx.x;
    const int row = gid >> 5;
    const int d0  = (gid & 31) << 3;
    const float4 a = *reinterpret_cast<const float4*>(X + (size_t)row * D_N + d0);
    const float4 b = *reinterpret_cast<const float4*>(X + (size_t)row * D_N + d0 + 4);
    float f[8] = {a.x, a.y, a.z, a.w, b.x, b.y, b.z, b.w};
    unsigned hi[8], lo[8];
    #pragma unroll
    for (int j = 0; j < 8; ++j) {
        hi[j] = f2bf(f[j]);
        lo[j] = f2bf(f[j] - bfhi2f((u16)hi[j]));
    }
    const int rb = row >> 7, r = row & 127, rf = r >> 4, llo = r & 15;
    const int dstep = d0 >> 6, dd = d0 & 63, ks = dd >> 5, lhi = (dd & 31) >> 3;
    const int lane = (lhi << 4) | llo;
    size_t base = (size_t)(rb * 4 + dstep) * 16384 + (size_t)((rf * 2 + ks) * 64 + lane) * 8;
    uint4v hv, lv;
    hv.x = hi[0] | (hi[1] << 16); hv.y = hi[2] | (hi[3] << 16);
    hv.z = hi[4] | (hi[5] << 16); hv.w = hi[6] | (hi[7] << 16);
    lv.x = lo[0] | (lo[1] << 16); lv.y = lo[2] | (lo[3] << 16);
    lv.z = lo[4] | (lo[5] << 16); lv.w = lo[6] | (lo[7] << 16);
    *reinterpret_cast<uint4v*>(Xsw + base) = hv;
    *reinterpret_cast<uint4v*>(Xsw + base + 8192) = lv;
}

__global__ void en2_f(const float* __restrict__ E, float* __restrict__ en2) {
    const int gtid = blockIdx.x * blockDim.x + threadIdx.x;
    const int wave = gtid >> 6;
    const int lane = threadIdx.x & 63;
    if (wave >= K_N) return;
    const float4 v = *reinterpret_cast<const float4*>(E + (size_t)wave * D_N + lane * 4);
    double s = (double)v.x * v.x + (double)v.y * v.y + (double)v.z * v.z + (double)v.w * v.w;
    #pragma unroll
    for (int o = 32; o; o >>= 1) s += __shfl_xor(s, o, 64);
    if (lane == 0) en2[wave] = (float)(0.5 * s);
}

__launch_bounds__(256, 2)
__global__ void dist_f(const u16* __restrict__ Xsw, const float* __restrict__ E,
                       const float* __restrict__ en2, float4* __restrict__ top2) {
    __shared__ __align__(16) u16 lds[32768];
    const int tid  = threadIdx.x;
    const int lane = tid & 63;
    const int wid  = tid >> 6;
    const int wr   = wid >> 1, wc = wid & 1;
    const int llo  = lane & 15, lhi = lane >> 4;
    const int rb = blockIdx.x;
    const int chunk = blockIdx.y;

    float tv0[16], tv1[16];
    int   tpk[16];
    #pragma unroll
    for (int s = 0; s < 16; ++s) { tv0[s] = 3.4e38f; tv1[s] = 3.4e38f; tpk[s] = -1; }

    const bf16x8* ldsv = reinterpret_cast<const bf16x8*>(lds);
    const char* xbase = reinterpret_cast<const char*>(Xsw) + (size_t)rb * 131072;

    for (int cb = 0; cb < 16; ++cb) {
        const int codebase = chunk * 2048 + cb * 128;
        f32x4 acc[4][4];
        #pragma unroll
        for (int i = 0; i < 4; ++i)
            #pragma unroll
            for (int j = 0; j < 4; ++j) acc[i][j] = (f32x4){0.f, 0.f, 0.f, 0.f};
        float en2v[4];
        #pragma unroll
        for (int j = 0; j < 4; ++j) en2v[j] = en2[codebase + (wc * 4 + j) * 16 + llo];

        for (int dstep = 0; dstep < 4; ++dstep) {
            __syncthreads();
            const char* xsrc = xbase + (size_t)dstep * 32768;
            #pragma unroll
            for (int it = 0; it < 8; ++it) {
                gload_lds16(xsrc + it * 4096 + wid * 1024 + lane * 16,
                            reinterpret_cast<char*>(lds) + it * 4096 + wid * 1024);
            }
            #pragma unroll
            for (int cfi = 0; cfi < 2; ++cfi) {
                const int cf = wid * 2 + cfi;
                const int code = codebase + cf * 16 + llo;
                #pragma unroll
                for (int ks = 0; ks < 2; ++ks) {
                    const int d = dstep * 64 + ks * 32 + lhi * 8;
                    const float* ep = E + (size_t)code * D_N + d;
                    const float4 ea = *reinterpret_cast<const float4*>(ep);
                    const float4 eb2 = *reinterpret_cast<const float4*>(ep + 4);
                    float f[8] = {ea.x, ea.y, ea.z, ea.w, eb2.x, eb2.y, eb2.z, eb2.w};
                    unsigned h2[8], l2[8];
                    #pragma unroll
                    for (int j = 0; j < 8; ++j) {
                        h2[j] = f2bf(f[j]);
                        l2[j] = f2bf(f[j] - bfhi2f((u16)h2[j]));
                    }
                    uint4v hv, lv;
                    hv.x = h2[0] | (h2[1] << 16); hv.y = h2[2] | (h2[3] << 16);
                    hv.z = h2[4] | (h2[5] << 16); hv.w = h2[6] | (h2[7] << 16);
                    lv.x = l2[0] | (l2[1] << 16); lv.y = l2[2] | (l2[3] << 16);
                    lv.z = l2[4] | (l2[5] << 16); lv.w = l2[6] | (l2[7] << 16);
                    const int uoff = 16384 + ((cf * 2 + ks) * 64 + lane) * 8;
                    *reinterpret_cast<uint4v*>(lds + uoff) = hv;
                    *reinterpret_cast<uint4v*>(lds + uoff + 8192) = lv;
                }
            }
            __syncthreads();

            #pragma unroll
            for (int ks = 0; ks < 2; ++ks) {
                bf16x8 ah[4], bh[4], al[4], bl[4];
                #pragma unroll
                for (int i = 0; i < 4; ++i) ah[i] = ldsv[((wr * 4 + i) * 2 + ks) * 64 + lane];
                #pragma unroll
                for (int j = 0; j < 4; ++j) bh[j] = ldsv[2048 + ((wc * 4 + j) * 2 + ks) * 64 + lane];
                #pragma unroll
                for (int i = 0; i < 4; ++i)
                    #pragma unroll
                    for (int j = 0; j < 4; ++j)
                        acc[i][j] = __builtin_amdgcn_mfma_f32_16x16x32_bf16(ah[i], bh[j], acc[i][j], 0, 0, 0);
                #pragma unroll
                for (int i = 0; i < 4; ++i) al[i] = ldsv[1024 + ((wr * 4 + i) * 2 + ks) * 64 + lane];
                #pragma unroll
                for (int i = 0; i < 4; ++i)
                    #pragma unroll
                    for (int j = 0; j < 4; ++j)
                        acc[i][j] = __builtin_amdgcn_mfma_f32_16x16x32_bf16(al[i], bh[j], acc[i][j], 0, 0, 0);
                #pragma unroll
                for (int j = 0; j < 4; ++j) bl[j] = ldsv[3072 + ((wc * 4 + j) * 2 + ks) * 64 + lane];
                #pragma unroll
                for (int i = 0; i < 4; ++i)
                    #pragma unroll
                    for (int j = 0; j < 4; ++j)
                        acc[i][j] = __builtin_amdgcn_mfma_f32_16x16x32_bf16(ah[i], bl[j], acc[i][j], 0, 0, 0);
            }
        }

        #pragma unroll
        for (int j = 0; j < 4; ++j) {
            const int idx = codebase + (wc * 4 + j) * 16 + llo;
            const float en = en2v[j];
            #pragma unroll
            for (int i = 0; i < 4; ++i) {
                #pragma unroll
                for (int r = 0; r < 4; ++r) {
                    const float v = en - 0.5f * acc[i][j][r] * 2.0f;  // == en - acc (kept simple)
                    const int s = i * 4 + r;
                    const bool c0 = v < tv0[s];
                    const bool c1 = v < tv1[s];
                    const int pk = tpk[s];
                    const int pkA = (pk << 16) | idx;
                    const int pkB = (idx << 16) | (pk & 0xffff);
                    tv1[s] = c0 ? tv0[s] : (c1 ? v : tv1[s]);
                    tv0[s] = c0 ? v : tv0[s];
                    tpk[s] = c0 ? pkA : (c1 ? pkB : pk);
                }
            }
        }
    }

    #pragma unroll
    for (int m = 1; m <= 8; m <<= 1) {
        #pragma unroll
        for (int s = 0; s < 16; ++s) {
            float ov0 = __shfl_xor(tv0[s], m, 64);
            float ov1 = __shfl_xor(tv1[s], m, 64);
            int   opk = __shfl_xor(tpk[s], m, 64);
            float v0 = tv0[s], v1 = tv1[s];
            int i0 = tpk[s] & 0xffff, i1 = (tpk[s] >> 16) & 0xffff;
            top2_merge(v0, i0, v1, i1, ov0, opk & 0xffff, ov1, (opk >> 16) & 0xffff);
            tv0[s] = v0; tv1[s] = v1; tpk[s] = (i1 << 16) | i0;
        }
    }

    __syncthreads();
    float4* M = reinterpret_cast<float4*>(lds);
    if (llo == 0) {
        #pragma unroll
        for (int i = 0; i < 4; ++i)
            #pragma unroll
            for (int r = 0; r < 4; ++r) {
                const int rowl = wr * 64 + i * 16 + lhi * 4 + r;
                const int s = i * 4 + r;
                M[rowl * 2 + wc] = make_float4(tv0[s], __int_as_float(tpk[s] & 0xffff),
                                               tv1[s], __int_as_float((tpk[s] >> 16) & 0xffff));
            }
    }
    __syncthreads();
    if (tid < 128) {
        float4 A4 = M[tid * 2 + 0], B4 = M[tid * 2 + 1];
        float v0 = A4.x, v1 = A4.z;
        int i0 = __float_as_int(A4.y), i1 = __float_as_int(A4.w);
        top2_merge(v0, i0, v1, i1, B4.x, __float_as_int(B4.y), B4.z, __float_as_int(B4.w));
        top2[(size_t)(rb * 128 + tid) * NCHF + chunk] =
            make_float4(v0, __int_as_float(i0), v1, __int_as_float(i1));
    }
}

// ================= launcher =================

extern "C" void kernel_launch(void* const* d_in, const int* in_sizes, int n_in,
                              void* d_out, int out_size, void* d_ws, size_t ws_size,
                              hipStream_t stream) {
    const float* X = (const float*)d_in[0];
    const float* E = (const float*)d_in[1];
    float* out = (float*)d_out;
    char* ws = (char*)d_ws;
    u16* Xsw = (u16*)d_out;   // 32 MiB scratch inside d_out (overwritten by rescore)

    if (ws_size >= P_NEED) {
        float4* top2     = (float4*)(ws + P_TOP2);
        u16*    Esw      = (u16*)(ws + P_ESW);
        u16*    Eext     = (u16*)(ws + P_EXT);
        double* partials = (double*)(ws + P_PART);

        xconv_kernel<<<(B_N * 32) / 256, 256, 0, stream>>>(X, Xsw);
        econv_kernel<<<(K_N * 32) / 256, 256, 0, stream>>>(E, Esw);
        en2ext_kernel<<<(K_N * 64) / 256, 256, 0, stream>>>(E, Eext);
        dist2_kernel<<<dim3(B_N / 128, NCH), 256, 0, stream>>>(
            (const char*)Xsw, (const char*)Esw, (const char*)Eext, top2);
        rescore_kernel<NCH><<<512, 256, 0, stream>>>(X, E, top2, out, partials);
        finalize_kernel<<<1, 256, 0, stream>>>(partials, 512, out + (size_t)B_N * D_N);
    } else {
        float4* top2     = (float4*)(ws + F_TOP2);
        float*  en2      = (float*)(ws + F_EN2);
        double* partials = (double*)(ws + F_PART);

        xconv_f<<<(B_N * 32) / 256, 256, 0, stream>>>(X, Xsw);
        en2_f<<<K_N / 4, 256, 0, stream>>>(E, en2);
        dist_f<<<dim3(B_N / 128, NCHF), 256, 0, stream>>>(Xsw, E, en2, top2);
        rescore_kernel<NCHF><<<512, 256, 0, stream>>>(X, E, top2, out, partials);
        finalize_kernel<<<1, 256, 0, stream>>>(partials, 512, out + (size_t)B_N * D_N);
    }
}